// Round 6
// baseline (269.907 us; speedup 1.0000x reference)
//
#include <hip/hip_runtime.h>
#include <cstdint>
#include <cstddef>

#define DEVINL __device__ __forceinline__

typedef short short8 __attribute__((ext_vector_type(8)));
typedef float f32x4 __attribute__((ext_vector_type(4)));
typedef unsigned short ushort;
typedef ushort u16x8 __attribute__((ext_vector_type(8)));
typedef ushort u16x4 __attribute__((ext_vector_type(4)));

DEVINL float bf2f(ushort u) {
  union { unsigned int i; float f; } v; v.i = ((unsigned int)u) << 16; return v.f;
}
DEVINL ushort f2bf(float f) {
  union { float f; unsigned int i; } v; v.f = f;
  unsigned int u = v.i;
  unsigned int r = u + 0x7fffu + ((u >> 16) & 1u);
  return (ushort)(r >> 16);
}

// Async global->LDS, 16B per lane. LDS dest = wave-uniform base + lane*16.
DEVINL void gl2lds16(const ushort* g, ushort* l) {
  __builtin_amdgcn_global_load_lds(
      (const __attribute__((address_space(1))) void*)g,
      (__attribute__((address_space(3))) void*)l, 16, 0, 0);
}

// ------- fused 6x weight transpose + cast: f32 [R,C] -> bf16 [C,R] ----
// z 0..3: 384x384 (Wq,Wk,Wv,Wp)  z==4: W1 384x1536  z==5: W2 1536x384
__global__ void transpose6_k(const float* __restrict__ Wq, const float* __restrict__ Wk,
                             const float* __restrict__ Wv, const float* __restrict__ Wp,
                             const float* __restrict__ W1, const float* __restrict__ W2,
                             ushort* __restrict__ WqT, ushort* __restrict__ WkT,
                             ushort* __restrict__ WvT, ushort* __restrict__ WpT,
                             ushort* __restrict__ W1T, ushort* __restrict__ W2T) {
  __shared__ float tile[32][33];
  int z = blockIdx.z;
  const float* in;
  ushort* out;
  int R, C, bx, by;
  if (z < 4) {
    if (blockIdx.x >= 12) return;  // uniform early-out, before any barrier
    in = (z == 0) ? Wq : (z == 1) ? Wk : (z == 2) ? Wv : Wp;
    out = (z == 0) ? WqT : (z == 1) ? WkT : (z == 2) ? WvT : WpT;
    R = 384; C = 384; bx = blockIdx.x; by = blockIdx.y;
  } else if (z == 4) {
    in = W1; out = W1T; R = 384; C = 1536; bx = blockIdx.x; by = blockIdx.y;
  } else {
    in = W2; out = W2T; R = 1536; C = 384; bx = blockIdx.y; by = blockIdx.x;
  }
  int tx = threadIdx.x, ty = threadIdx.y;  // (32,8)
  int x = bx * 32 + tx;
#pragma unroll
  for (int i = 0; i < 4; i++) {
    int y = by * 32 + ty + i * 8;
    tile[ty + i * 8][tx] = in[(size_t)y * C + x];
  }
  __syncthreads();
  int x2 = by * 32 + tx;
#pragma unroll
  for (int i = 0; i < 4; i++) {
    int y2 = bx * 32 + ty + i * 8;
    out[(size_t)y2 * R + x2] = f2bf(tile[tx][ty + i * 8]);
  }
}

// ------- LayerNorm: wave per row of 384; fp32 in -> bf16 out ----
__global__ __launch_bounds__(256) void ln_k(const float* __restrict__ x,
                                            const float* __restrict__ g,
                                            const float* __restrict__ b,
                                            ushort* __restrict__ out) {
  int wave = threadIdx.x >> 6;
  int lane = threadIdx.x & 63;
  int row = blockIdx.x * 4 + wave;
  const float* xr = x + (size_t)row * 384;
  float v[6];
#pragma unroll
  for (int j = 0; j < 3; j++) {
    float2 p = *(const float2*)(xr + lane * 2 + j * 128);
    v[2 * j] = p.x;
    v[2 * j + 1] = p.y;
  }
  float s = v[0] + v[1] + v[2] + v[3] + v[4] + v[5];
#pragma unroll
  for (int off = 32; off; off >>= 1) s += __shfl_xor(s, off);
  float mu = s * (1.0f / 384.0f);
  float s2 = 0.f;
#pragma unroll
  for (int j = 0; j < 6; j++) { float d = v[j] - mu; s2 += d * d; }
#pragma unroll
  for (int off = 32; off; off >>= 1) s2 += __shfl_xor(s2, off);
  float rs = rsqrtf(s2 * (1.0f / 384.0f) + 1e-5f);
  ushort* orow = out + (size_t)row * 384;
#pragma unroll
  for (int j = 0; j < 3; j++) {
    int c = lane * 2 + j * 128;
    float2 pg = *(const float2*)(g + c);
    float2 pb = *(const float2*)(b + c);
    float y0 = (v[2 * j] - mu) * rs * pg.x + pb.x;
    float y1 = (v[2 * j + 1] - mu) * rs * pg.y + pb.y;
    uint32_t po = (uint32_t)f2bf(y0) | ((uint32_t)f2bf(y1) << 16);
    *(uint32_t*)(orow + c) = po;
  }
}

// ------- GEMM: C[M,N] = A[M,K](bf16) @ W[K,N], W as bf16 WT[N,K] ----
// BK=64, XOR-8 chunk swizzle staging: LDS slot s of row r holds global
// chunk s^(r&7); fragment reads use slot (ks*4+q4)^(r&7) -> conflict-free
// b128 reads. 128xTN tiles, 32KB LDS, multiple blocks/CU -> cross-block
// TLP hides staging (the proven ~12 TB/s structure; 1-block/CU designs
// measured 8 TB/s regardless of pipelining, R2-R5).
// MODE 0 (TN=128): QKV — grid.z selects Wq/Wk/Wv; q (pre-scaled by
//                  0.125*log2e), k -> [B,H,T,D]; v -> [B,H,D,T]
// MODE 1 (TN=128): outf = A@W + bias + residf (fp32 epilogue, ld 384)
//                  [proj, ff2; in-place-safe: each idx read+written by
//                  exactly one thread]
// MODE 2 (TN=128): outa = bf16(relu(A@W + bias)) (ld 1536)  [ff1]
template <int MODE, int TN>
__global__ __launch_bounds__(256) void gemm_k(
    const ushort* __restrict__ A, int K,
    const ushort* __restrict__ WTa, const ushort* __restrict__ WTb,
    const ushort* __restrict__ WTc,
    const float* __restrict__ bias, const float* residf,
    ushort* __restrict__ outa, ushort* __restrict__ outb,
    ushort* __restrict__ outc, float* outf) {
  constexpr int NJ = TN / 32;
  __shared__ __align__(16) ushort As[128 * 64];
  __shared__ __align__(16) ushort Bs[TN * 64];
  int tid = threadIdx.x;
  int lane = tid & 63, wave = tid >> 6;
  int wm = wave & 1, wn = wave >> 1;
  int q4 = lane >> 4, ln16 = lane & 15;
  int rowBase = blockIdx.x * 128;
  int colBase = blockIdx.y * TN;

  const ushort* WT;
  if (MODE == 0) {
    int z = blockIdx.z;
    WT = (z == 0) ? WTa : (z == 1) ? WTb : WTc;
  } else {
    WT = WTa;
  }

  f32x4 acc[4][NJ];
#pragma unroll
  for (int i = 0; i < 4; i++)
#pragma unroll
    for (int j = 0; j < NJ; j++) acc[i][j] = (f32x4){0.f, 0.f, 0.f, 0.f};

  int ri = lane >> 3;             // row within 8-row issue group
  int g8 = (lane & 7) ^ ri;       // swizzled global 8-elem chunk

  for (int kb = 0; kb < K; kb += 64) {
#pragma unroll
    for (int h = 0; h < 128; h += 32) {
      int base = h + wave * 8;
      gl2lds16(&A[(size_t)(rowBase + base + ri) * K + kb + g8 * 8], &As[base * 64]);
    }
#pragma unroll
    for (int h = 0; h < TN; h += 32) {
      int base = h + wave * 8;
      gl2lds16(&WT[(size_t)(colBase + base + ri) * K + kb + g8 * 8], &Bs[base * 64]);
    }
    __syncthreads();
#pragma unroll
    for (int ks = 0; ks < 2; ks++) {
      short8 af[4], bfr[NJ];
#pragma unroll
      for (int i = 0; i < 4; i++) {
        int ar = wm * 64 + i * 16 + ln16;
        int slot = (ks * 4 + q4) ^ (ar & 7);
        af[i] = *(const short8*)&As[ar * 64 + slot * 8];
      }
#pragma unroll
      for (int j = 0; j < NJ; j++) {
        int br = wn * (TN / 2) + j * 16 + ln16;
        int slot = (ks * 4 + q4) ^ (br & 7);
        bfr[j] = *(const short8*)&Bs[br * 64 + slot * 8];
      }
#pragma unroll
      for (int i = 0; i < 4; i++)
#pragma unroll
        for (int j = 0; j < NJ; j++)
          acc[i][j] = __builtin_amdgcn_mfma_f32_16x16x32_bf16(af[i], bfr[j], acc[i][j], 0, 0, 0);
    }
    __syncthreads();
  }

#pragma unroll
  for (int i = 0; i < 4; i++) {
#pragma unroll
    for (int j = 0; j < NJ; j++) {
      int row0 = rowBase + wm * 64 + i * 16 + q4 * 4;
      int col = colBase + wn * (TN / 2) + j * 16 + ln16;
      if (MODE == 0) {
        int z = blockIdx.z;
        if (z < 2) {
          // q is pre-scaled by qk-scale * log2(e) so attention skips the mul
          float sc = (z == 0) ? 0.18033688011112f : 1.0f;
          ushort* o = (z == 0) ? outa : outb;
#pragma unroll
          for (int r = 0; r < 4; r++) {
            int row = row0 + r;
            int bb = row >> 9, t = row & 511, h = col >> 6, d = col & 63;
            o[(((size_t)(bb * 6 + h) * 512) + t) * 64 + d] = f2bf(acc[i][j][r] * sc);
          }
        } else {
          int bb = row0 >> 9, t0 = row0 & 511, h = col >> 6, d = col & 63;
          u16x4 pk = {f2bf(acc[i][j][0]), f2bf(acc[i][j][1]), f2bf(acc[i][j][2]),
                      f2bf(acc[i][j][3])};
          *(u16x4*)&outc[(((size_t)(bb * 6 + h) * 64) + d) * 512 + t0] = pk;
        }
      } else if (MODE == 1) {
        float bcol = bias[col];
#pragma unroll
        for (int r = 0; r < 4; r++) {
          size_t idx = (size_t)(row0 + r) * 384 + col;
          outf[idx] = acc[i][j][r] + bcol + residf[idx];
        }
      } else {
        float bcol = bias[col];
#pragma unroll
        for (int r = 0; r < 4; r++) {
          size_t idx = (size_t)(row0 + r) * 1536 + col;
          float vv = acc[i][j][r] + bcol;
          outa[idx] = f2bf(vv > 0.f ? vv : 0.f);
        }
      }
    }
  }
}

// ------- flash attention, paired q-tiles + XCD-local bh ----
// Block handles q-tiles pr and 7-pr of one (b,h): uniform work (9 units),
// shared K/V staging. S^T = K·Q^T; softmax in-register; O^T = V^T·P^T.
// K/V staged via global_load_lds with XOR-8 chunk swizzle (linear [64][64]
// LDS, slot s of row r = global chunk s^(r&7)) -> conflict-free b128 reads.
// Q pre-scaled at QKV epilogue; causal mask applied only on diagonal tile;
// T13 defer-rescale skips O-rescale while running max grows < 8 (log2 dom).
__global__ __launch_bounds__(256) void attn_k(const ushort* __restrict__ qg,
                                              const ushort* __restrict__ kg,
                                              const ushort* __restrict__ vtg,
                                              ushort* __restrict__ outg) {
  __shared__ __align__(16) ushort Ks[64 * 64];
  __shared__ __align__(16) ushort VTs[64 * 64];
  __shared__ __align__(16) ushort Pw[4][16][88];
  int tid = threadIdx.x, lane = tid & 63, wave = tid >> 6;
  int l = blockIdx.x;
  int xcd = l & 7, m = l >> 3;
  int bh = xcd * 24 + (m >> 2);
  int pr = m & 3;           // pair index: q-tiles pr (lo) and 7-pr (hi)
  int lo = pr, hi = 7 - pr;
  int quad = lane >> 4, ln16 = lane & 15;
  int x7 = ln16 & 7;
  int slo = (quad ^ x7) * 8;   // swizzled elem offset, cols 0..31
  int shi = slo ^ 32;          // cols 32..63 ((quad+4)^x7 == (quad^x7)^4)

  const ushort* qp = qg + (size_t)bh * 512 * 64;
  const ushort* kp = kg + (size_t)bh * 512 * 64;
  const ushort* vp = vtg + (size_t)bh * 64 * 512;

  int ri = lane >> 3;          // row within 8-row issue group
  int g8 = (lane & 7) ^ ri;    // swizzled global 8-elem chunk

  int t_lo = lo * 64 + wave * 16 + ln16;
  int t_hi = hi * 64 + wave * 16 + ln16;
  short8 bqlo0 = *(const short8*)&qp[(size_t)t_lo * 64 + quad * 8];
  short8 bqlo1 = *(const short8*)&qp[(size_t)t_lo * 64 + 32 + quad * 8];
  short8 bqhi0 = *(const short8*)&qp[(size_t)t_hi * 64 + quad * 8];
  short8 bqhi1 = *(const short8*)&qp[(size_t)t_hi * 64 + 32 + quad * 8];

  f32x4 Olo[4], Ohi[4];
#pragma unroll
  for (int dt = 0; dt < 4; dt++) {
    Olo[dt] = (f32x4){0.f, 0.f, 0.f, 0.f};
    Ohi[dt] = (f32x4){0.f, 0.f, 0.f, 0.f};
  }
  float m_lo = -3.0e38f, l_lo = 0.f, m_hi = -3.0e38f, l_hi = 0.f;

  auto process = [&](short8 q0f, short8 q1f, int t_row, float& m_, float& l_,
                     f32x4* O, int s0, bool maskit) {
    f32x4 St[4];
    __builtin_amdgcn_s_setprio(1);
#pragma unroll
    for (int kt = 0; kt < 4; kt++) {
      int r = kt * 16 + ln16;
      short8 a0 = *(const short8*)&Ks[r * 64 + slo];
      short8 a1 = *(const short8*)&Ks[r * 64 + shi];
      f32x4 z = (f32x4){0.f, 0.f, 0.f, 0.f};
      z = __builtin_amdgcn_mfma_f32_16x16x32_bf16(a0, q0f, z, 0, 0, 0);
      z = __builtin_amdgcn_mfma_f32_16x16x32_bf16(a1, q1f, z, 0, 0, 0);
      St[kt] = z;
    }
    __builtin_amdgcn_s_setprio(0);
    if (maskit) {  // uniform branch: only the diagonal tile needs the mask
#pragma unroll
      for (int kt = 0; kt < 4; kt++)
#pragma unroll
        for (int r = 0; r < 4; r++) {
          int s_abs = s0 + kt * 16 + quad * 4 + r;
          St[kt][r] = (s_abs <= t_row) ? St[kt][r] : -3.0e38f;
        }
    }
    float vm = St[0][0];
#pragma unroll
    for (int kt = 0; kt < 4; kt++)
#pragma unroll
      for (int r = 0; r < 4; r++) vm = fmaxf(vm, St[kt][r]);
    vm = fmaxf(vm, __shfl_xor(vm, 16));
    vm = fmaxf(vm, __shfl_xor(vm, 32));
    float mn = fmaxf(m_, vm);
    // T13 defer-rescale: keep old max while growth < 8 (p <= 2^8, safe in f32)
    if (!__all(mn - m_ <= 8.0f)) {
      float alpha = exp2f(m_ - mn);
      m_ = mn;
      l_ *= alpha;
#pragma unroll
      for (int dt = 0; dt < 4; dt++)
#pragma unroll
        for (int r = 0; r < 4; r++) O[dt][r] *= alpha;
    }
    float ps = 0.f;
#pragma unroll
    for (int kt = 0; kt < 4; kt++)
#pragma unroll
      for (int r = 0; r < 4; r++) {
        float p = exp2f(St[kt][r] - m_);
        St[kt][r] = p;
        ps += p;
      }
    ps += __shfl_xor(ps, 16);
    ps += __shfl_xor(ps, 32);
    l_ += ps;

    asm volatile("" ::: "memory");  // order Pw writes after prior Pw reads
#pragma unroll
    for (int kt = 0; kt < 4; kt++) {
      u16x4 pk = {f2bf(St[kt][0]), f2bf(St[kt][1]), f2bf(St[kt][2]), f2bf(St[kt][3])};
      *(u16x4*)&Pw[wave][ln16][kt * 16 + quad * 4] = pk;
    }
    asm volatile("" ::: "memory");  // forbid hoisting Pw reads above writes
    union { u16x8 u; short8 s; } p0, p1;
    p0.u = *(const u16x8*)&Pw[wave][ln16][quad * 8];
    p1.u = *(const u16x8*)&Pw[wave][ln16][32 + quad * 8];
    __builtin_amdgcn_s_setprio(1);
#pragma unroll
    for (int dt = 0; dt < 4; dt++) {
      int r = dt * 16 + ln16;
      short8 v0 = *(const short8*)&VTs[r * 64 + slo];
      short8 v1 = *(const short8*)&VTs[r * 64 + shi];
      O[dt] = __builtin_amdgcn_mfma_f32_16x16x32_bf16(v0, p0.s, O[dt], 0, 0, 0);
      O[dt] = __builtin_amdgcn_mfma_f32_16x16x32_bf16(v1, p1.s, O[dt], 0, 0, 0);
    }
    __builtin_amdgcn_s_setprio(0);
  };

  for (int s0 = 0; s0 <= hi * 64; s0 += 64) {
    // stage K tile [64][64] + V^T tile [64][64] via async global->LDS,
    // 8 rows per issue, 2 issues per wave per array
#pragma unroll
    for (int h = 0; h < 64; h += 32) {
      int base = h + wave * 8;
      gl2lds16(&kp[(size_t)(s0 + base + ri) * 64 + g8 * 8], &Ks[base * 64]);
      gl2lds16(&vp[(size_t)(base + ri) * 512 + s0 + g8 * 8], &VTs[base * 64]);
    }
    __syncthreads();
    if (s0 <= lo * 64) process(bqlo0, bqlo1, t_lo, m_lo, l_lo, Olo, s0, s0 == lo * 64);
    process(bqhi0, bqhi1, t_hi, m_hi, l_hi, Ohi, s0, s0 == hi * 64);
    __syncthreads();
  }

  int b = bh / 6, h = bh % 6;
  float ilo = 1.0f / l_lo, ihi = 1.0f / l_hi;
  size_t base_lo = ((size_t)(b * 512) + t_lo) * 384 + h * 64;
  size_t base_hi = ((size_t)(b * 512) + t_hi) * 384 + h * 64;
#pragma unroll
  for (int dt = 0; dt < 4; dt++) {
    u16x4 plo = {f2bf(Olo[dt][0] * ilo), f2bf(Olo[dt][1] * ilo),
                 f2bf(Olo[dt][2] * ilo), f2bf(Olo[dt][3] * ilo)};
    *(u16x4*)&outg[base_lo + dt * 16 + quad * 4] = plo;
    u16x4 phi = {f2bf(Ohi[dt][0] * ihi), f2bf(Ohi[dt][1] * ihi),
                 f2bf(Ohi[dt][2] * ihi), f2bf(Ohi[dt][3] * ihi)};
    *(u16x4*)&outg[base_hi + dt * 16 + quad * 4] = phi;
  }
}

// ---------------- host ----------------
extern "C" void kernel_launch(void* const* d_in, const int* in_sizes, int n_in,
                              void* d_out, int out_size, void* d_ws, size_t ws_size,
                              hipStream_t stream) {
  const float* x = (const float*)d_in[0];
  const float* Wq = (const float*)d_in[1];
  const float* Wk = (const float*)d_in[2];
  const float* Wv = (const float*)d_in[3];
  const float* Wp = (const float*)d_in[4];
  const float* bp = (const float*)d_in[5];
  const float* g1 = (const float*)d_in[6];
  const float* b1 = (const float*)d_in[7];
  const float* g2 = (const float*)d_in[8];
  const float* b2 = (const float*)d_in[9];
  const float* W1 = (const float*)d_in[10];
  const float* bf1 = (const float*)d_in[11];
  const float* W2 = (const float*)d_in[12];
  const float* bf2 = (const float*)d_in[13];
  float* outp = (float*)d_out;  // fp32 output; also hosts xr between proj and ff2

  char* ws = (char*)d_ws;
  size_t off = 0;
  auto alloc = [&](size_t elems) {
    ushort* p = (ushort*)(ws + off);
    off += elems * 2;
    return p;
  };
  ushort* WqT = alloc((size_t)384 * 384);
  ushort* WkT = alloc((size_t)384 * 384);
  ushort* WvT = alloc((size_t)384 * 384);
  ushort* WpT = alloc((size_t)384 * 384);
  ushort* W1T = alloc((size_t)384 * 1536);
  ushort* W2T = alloc((size_t)1536 * 384);
  ushort* bufq = alloc((size_t)16384 * 384);  // q, later h2
  ushort* m1 = alloc((size_t)16384 * 1536);   // [h1/attn | k | vT | spare], then ff1
  ushort* h1_attn = m1;
  ushort* bufk = m1 + (size_t)16384 * 384;
  ushort* vT = m1 + (size_t)2 * 16384 * 384;

  dim3 tb(32, 8);
  // all 6 weight transposes in one launch
  transpose6_k<<<dim3(48, 12, 6), tb, 0, stream>>>(Wq, Wk, Wv, Wp, W1, W2,
                                                   WqT, WkT, WvT, WpT, W1T, W2T);

  // h1 = ln(x, g1, b1)  [fp32 -> bf16]
  ln_k<<<4096, 256, 0, stream>>>(x, g1, b1, h1_attn);
  // q,k,vT (bf16); q pre-scaled by 0.125*log2(e)
  gemm_k<0, 128><<<dim3(128, 3, 3), 256, 0, stream>>>(
      h1_attn, 384, WqT, WkT, WvT, nullptr, nullptr, bufq, bufk, vT, nullptr);
  // attention -> attn (bf16, overwrites h1 slot)
  attn_k<<<768, 256, 0, stream>>>(bufq, bufk, vT, h1_attn);
  // xr = attn@Wp + bp + x  (fp32, into d_out)
  gemm_k<1, 128><<<dim3(128, 3), 256, 0, stream>>>(
      h1_attn, 384, WpT, nullptr, nullptr, bp, x, nullptr, nullptr, nullptr, outp);
  // h2 = ln(xr, g2, b2)  [fp32 -> bf16, into q slot]
  ln_k<<<4096, 256, 0, stream>>>(outp, g2, b2, bufq);
  // m1 = relu(h2@W1 + bf1)  (bf16)
  gemm_k<2, 128><<<dim3(128, 12), 256, 0, stream>>>(
      bufq, 384, W1T, nullptr, nullptr, bf1, nullptr, m1, nullptr, nullptr, nullptr);
  // out = m1@W2 + bf2 + xr  (fp32, in-place on d_out)
  gemm_k<1, 128><<<dim3(128, 3), 256, 0, stream>>>(
      m1, 1536, W2T, nullptr, nullptr, bf2, outp, nullptr, nullptr, nullptr, outp);
}

// Round 7
// 253.040 us; speedup vs baseline: 1.0667x; 1.0667x over previous
//
#include <hip/hip_runtime.h>
#include <cstdint>
#include <cstddef>

#define DEVINL __device__ __forceinline__

typedef short short8 __attribute__((ext_vector_type(8)));
typedef float f32x4 __attribute__((ext_vector_type(4)));
typedef unsigned short ushort;
typedef ushort u16x8 __attribute__((ext_vector_type(8)));
typedef ushort u16x4 __attribute__((ext_vector_type(4)));

DEVINL float bf2f(ushort u) {
  union { unsigned int i; float f; } v; v.i = ((unsigned int)u) << 16; return v.f;
}
DEVINL ushort f2bf(float f) {
  union { float f; unsigned int i; } v; v.f = f;
  unsigned int u = v.i;
  unsigned int r = u + 0x7fffu + ((u >> 16) & 1u);
  return (ushort)(r >> 16);
}

// Async global->LDS, 16B per lane. LDS dest = wave-uniform base + lane*16.
DEVINL void gl2lds16(const ushort* g, ushort* l) {
  __builtin_amdgcn_global_load_lds(
      (const __attribute__((address_space(1))) void*)g,
      (__attribute__((address_space(3))) void*)l, 16, 0, 0);
}

// ------- fused 6x weight transpose + cast: f32 [R,C] -> bf16 [C,R] ----
// z 0..3: 384x384 (Wq,Wk,Wv,Wp)  z==4: W1 384x1536  z==5: W2 1536x384
__global__ void transpose6_k(const float* __restrict__ Wq, const float* __restrict__ Wk,
                             const float* __restrict__ Wv, const float* __restrict__ Wp,
                             const float* __restrict__ W1, const float* __restrict__ W2,
                             ushort* __restrict__ WqT, ushort* __restrict__ WkT,
                             ushort* __restrict__ WvT, ushort* __restrict__ WpT,
                             ushort* __restrict__ W1T, ushort* __restrict__ W2T) {
  __shared__ float tile[32][33];
  int z = blockIdx.z;
  const float* in;
  ushort* out;
  int R, C, bx, by;
  if (z < 4) {
    if (blockIdx.x >= 12) return;  // uniform early-out, before any barrier
    in = (z == 0) ? Wq : (z == 1) ? Wk : (z == 2) ? Wv : Wp;
    out = (z == 0) ? WqT : (z == 1) ? WkT : (z == 2) ? WvT : WpT;
    R = 384; C = 384; bx = blockIdx.x; by = blockIdx.y;
  } else if (z == 4) {
    in = W1; out = W1T; R = 384; C = 1536; bx = blockIdx.x; by = blockIdx.y;
  } else {
    in = W2; out = W2T; R = 1536; C = 384; bx = blockIdx.y; by = blockIdx.x;
  }
  int tx = threadIdx.x, ty = threadIdx.y;  // (32,8)
  int x = bx * 32 + tx;
#pragma unroll
  for (int i = 0; i < 4; i++) {
    int y = by * 32 + ty + i * 8;
    tile[ty + i * 8][tx] = in[(size_t)y * C + x];
  }
  __syncthreads();
  int x2 = by * 32 + tx;
#pragma unroll
  for (int i = 0; i < 4; i++) {
    int y2 = bx * 32 + ty + i * 8;
    out[(size_t)y2 * R + x2] = f2bf(tile[tx][ty + i * 8]);
  }
}

// ------- LayerNorm: wave per row of 384; fp32 in -> bf16 out ----
__global__ __launch_bounds__(256) void ln_k(const float* __restrict__ x,
                                            const float* __restrict__ g,
                                            const float* __restrict__ b,
                                            ushort* __restrict__ out) {
  int wave = threadIdx.x >> 6;
  int lane = threadIdx.x & 63;
  int row = blockIdx.x * 4 + wave;
  const float* xr = x + (size_t)row * 384;
  float v[6];
#pragma unroll
  for (int j = 0; j < 3; j++) {
    float2 p = *(const float2*)(xr + lane * 2 + j * 128);
    v[2 * j] = p.x;
    v[2 * j + 1] = p.y;
  }
  float s = v[0] + v[1] + v[2] + v[3] + v[4] + v[5];
#pragma unroll
  for (int off = 32; off; off >>= 1) s += __shfl_xor(s, off);
  float mu = s * (1.0f / 384.0f);
  float s2 = 0.f;
#pragma unroll
  for (int j = 0; j < 6; j++) { float d = v[j] - mu; s2 += d * d; }
#pragma unroll
  for (int off = 32; off; off >>= 1) s2 += __shfl_xor(s2, off);
  float rs = rsqrtf(s2 * (1.0f / 384.0f) + 1e-5f);
  ushort* orow = out + (size_t)row * 384;
#pragma unroll
  for (int j = 0; j < 3; j++) {
    int c = lane * 2 + j * 128;
    float2 pg = *(const float2*)(g + c);
    float2 pb = *(const float2*)(b + c);
    float y0 = (v[2 * j] - mu) * rs * pg.x + pb.x;
    float y1 = (v[2 * j + 1] - mu) * rs * pg.y + pb.y;
    uint32_t po = (uint32_t)f2bf(y0) | ((uint32_t)f2bf(y1) << 16);
    *(uint32_t*)(orow + c) = po;
  }
}

// ------- GEMM: C[M,N] = A[M,K](bf16) @ W[K,N], W as bf16 WT[N,K] ----
// BK=64, XOR-8 chunk swizzle staging: LDS slot s of row r holds global
// chunk s^(r&7); fragment reads use slot (ks*4+q4)^(r&7) -> conflict-free
// b128 reads. Staging BW is CONCURRENCY-limited (R2-R6: ~12 TB/s at
// 3 blocks/CU, 5.7-8 TB/s at <=1.5) -> keep >=768 blocks, small LDS.
// MODE 0 (TN=128, KU=1): QKV — grid.z selects Wq/Wk/Wv; q (pre-scaled by
//                  0.125*log2e), k -> [B,H,T,D]; v -> [B,H,D,T]
// MODE 1 (TN=64, KU=2): outf = A@W + bias + residf (fp32, ld 384)
//                  [proj, ff2]. KU=2: two 64-K sub-tiles staged per
//                  barrier pair (48KB LDS -> still 3 blocks/CU) halves
//                  the vmcnt-drain count; swizzle reused per sub-tile.
// MODE 2 (TN=128, KU=1): outa = bf16(relu(A@W + bias)) (ld 1536)  [ff1]
//                  (KU=2 at TN=128 would need 64KB LDS -> 2 blocks/CU,
//                  an occupancy regression — the m132 trap. Keep KU=1.)
template <int MODE, int TN>
__global__ __launch_bounds__(256) void gemm_k(
    const ushort* __restrict__ A, int K,
    const ushort* __restrict__ WTa, const ushort* __restrict__ WTb,
    const ushort* __restrict__ WTc,
    const float* __restrict__ bias, const float* residf,
    ushort* __restrict__ outa, ushort* __restrict__ outb,
    ushort* __restrict__ outc, float* outf) {
  constexpr int NJ = TN / 32;
  constexpr int KU = (MODE == 1) ? 2 : 1;  // K-sub-tiles per barrier pair
  __shared__ __align__(16) ushort As[KU][128 * 64];
  __shared__ __align__(16) ushort Bs[KU][TN * 64];
  int tid = threadIdx.x;
  int lane = tid & 63, wave = tid >> 6;
  int wm = wave & 1, wn = wave >> 1;
  int q4 = lane >> 4, ln16 = lane & 15;
  int rowBase = blockIdx.x * 128;
  int colBase = blockIdx.y * TN;

  const ushort* WT;
  if (MODE == 0) {
    int z = blockIdx.z;
    WT = (z == 0) ? WTa : (z == 1) ? WTb : WTc;
  } else {
    WT = WTa;
  }

  f32x4 acc[4][NJ];
#pragma unroll
  for (int i = 0; i < 4; i++)
#pragma unroll
    for (int j = 0; j < NJ; j++) acc[i][j] = (f32x4){0.f, 0.f, 0.f, 0.f};

  int ri = lane >> 3;             // row within 8-row issue group
  int g8 = (lane & 7) ^ ri;       // swizzled global 8-elem chunk

  for (int kb = 0; kb < K; kb += 64 * KU) {
#pragma unroll
    for (int u = 0; u < KU; u++) {
      int kk = kb + u * 64;
#pragma unroll
      for (int h = 0; h < 128; h += 32) {
        int base = h + wave * 8;
        gl2lds16(&A[(size_t)(rowBase + base + ri) * K + kk + g8 * 8], &As[u][base * 64]);
      }
#pragma unroll
      for (int h = 0; h < TN; h += 32) {
        int base = h + wave * 8;
        gl2lds16(&WT[(size_t)(colBase + base + ri) * K + kk + g8 * 8], &Bs[u][base * 64]);
      }
    }
    __syncthreads();
#pragma unroll
    for (int u = 0; u < KU; u++) {
#pragma unroll
      for (int ks = 0; ks < 2; ks++) {
        short8 af[4], bfr[NJ];
#pragma unroll
        for (int i = 0; i < 4; i++) {
          int ar = wm * 64 + i * 16 + ln16;
          int slot = (ks * 4 + q4) ^ (ar & 7);
          af[i] = *(const short8*)&As[u][ar * 64 + slot * 8];
        }
#pragma unroll
        for (int j = 0; j < NJ; j++) {
          int br = wn * (TN / 2) + j * 16 + ln16;
          int slot = (ks * 4 + q4) ^ (br & 7);
          bfr[j] = *(const short8*)&Bs[u][br * 64 + slot * 8];
        }
#pragma unroll
        for (int i = 0; i < 4; i++)
#pragma unroll
          for (int j = 0; j < NJ; j++)
            acc[i][j] = __builtin_amdgcn_mfma_f32_16x16x32_bf16(af[i], bfr[j], acc[i][j], 0, 0, 0);
      }
    }
    __syncthreads();
  }

#pragma unroll
  for (int i = 0; i < 4; i++) {
#pragma unroll
    for (int j = 0; j < NJ; j++) {
      int row0 = rowBase + wm * 64 + i * 16 + q4 * 4;
      int col = colBase + wn * (TN / 2) + j * 16 + ln16;
      if (MODE == 0) {
        int z = blockIdx.z;
        if (z < 2) {
          // q is pre-scaled by qk-scale * log2(e) so attention skips the mul
          float sc = (z == 0) ? 0.18033688011112f : 1.0f;
          ushort* o = (z == 0) ? outa : outb;
#pragma unroll
          for (int r = 0; r < 4; r++) {
            int row = row0 + r;
            int bb = row >> 9, t = row & 511, h = col >> 6, d = col & 63;
            o[(((size_t)(bb * 6 + h) * 512) + t) * 64 + d] = f2bf(acc[i][j][r] * sc);
          }
        } else {
          int bb = row0 >> 9, t0 = row0 & 511, h = col >> 6, d = col & 63;
          u16x4 pk = {f2bf(acc[i][j][0]), f2bf(acc[i][j][1]), f2bf(acc[i][j][2]),
                      f2bf(acc[i][j][3])};
          *(u16x4*)&outc[(((size_t)(bb * 6 + h) * 64) + d) * 512 + t0] = pk;
        }
      } else if (MODE == 1) {
        float bcol = bias[col];
#pragma unroll
        for (int r = 0; r < 4; r++) {
          size_t idx = (size_t)(row0 + r) * 384 + col;
          outf[idx] = acc[i][j][r] + bcol + residf[idx];
        }
      } else {
        float bcol = bias[col];
#pragma unroll
        for (int r = 0; r < 4; r++) {
          size_t idx = (size_t)(row0 + r) * 1536 + col;
          float vv = acc[i][j][r] + bcol;
          outa[idx] = f2bf(vv > 0.f ? vv : 0.f);
        }
      }
    }
  }
}

// ------- flash attention, paired q-tiles + XCD-local bh ----
// Block handles q-tiles pr and 7-pr of one (b,h): uniform work (9 units),
// shared K/V staging. S^T = K·Q^T; softmax in-register; O^T = V^T·P^T.
// K/V staged via global_load_lds with XOR-8 chunk swizzle (linear [64][64]
// LDS, slot s of row r = global chunk s^(r&7)) -> conflict-free b128 reads.
// Q pre-scaled at QKV epilogue; causal mask applied only on diagonal tile;
// T13 defer-rescale skips O-rescale while running max grows < 8 (log2 dom).
__global__ __launch_bounds__(256) void attn_k(const ushort* __restrict__ qg,
                                              const ushort* __restrict__ kg,
                                              const ushort* __restrict__ vtg,
                                              ushort* __restrict__ outg) {
  __shared__ __align__(16) ushort Ks[64 * 64];
  __shared__ __align__(16) ushort VTs[64 * 64];
  __shared__ __align__(16) ushort Pw[4][16][88];
  int tid = threadIdx.x, lane = tid & 63, wave = tid >> 6;
  int l = blockIdx.x;
  int xcd = l & 7, m = l >> 3;
  int bh = xcd * 24 + (m >> 2);
  int pr = m & 3;           // pair index: q-tiles pr (lo) and 7-pr (hi)
  int lo = pr, hi = 7 - pr;
  int quad = lane >> 4, ln16 = lane & 15;
  int x7 = ln16 & 7;
  int slo = (quad ^ x7) * 8;   // swizzled elem offset, cols 0..31
  int shi = slo ^ 32;          // cols 32..63 ((quad+4)^x7 == (quad^x7)^4)

  const ushort* qp = qg + (size_t)bh * 512 * 64;
  const ushort* kp = kg + (size_t)bh * 512 * 64;
  const ushort* vp = vtg + (size_t)bh * 64 * 512;

  int ri = lane >> 3;          // row within 8-row issue group
  int g8 = (lane & 7) ^ ri;    // swizzled global 8-elem chunk

  int t_lo = lo * 64 + wave * 16 + ln16;
  int t_hi = hi * 64 + wave * 16 + ln16;
  short8 bqlo0 = *(const short8*)&qp[(size_t)t_lo * 64 + quad * 8];
  short8 bqlo1 = *(const short8*)&qp[(size_t)t_lo * 64 + 32 + quad * 8];
  short8 bqhi0 = *(const short8*)&qp[(size_t)t_hi * 64 + quad * 8];
  short8 bqhi1 = *(const short8*)&qp[(size_t)t_hi * 64 + 32 + quad * 8];

  f32x4 Olo[4], Ohi[4];
#pragma unroll
  for (int dt = 0; dt < 4; dt++) {
    Olo[dt] = (f32x4){0.f, 0.f, 0.f, 0.f};
    Ohi[dt] = (f32x4){0.f, 0.f, 0.f, 0.f};
  }
  float m_lo = -3.0e38f, l_lo = 0.f, m_hi = -3.0e38f, l_hi = 0.f;

  auto process = [&](short8 q0f, short8 q1f, int t_row, float& m_, float& l_,
                     f32x4* O, int s0, bool maskit) {
    f32x4 St[4];
    __builtin_amdgcn_s_setprio(1);
#pragma unroll
    for (int kt = 0; kt < 4; kt++) {
      int r = kt * 16 + ln16;
      short8 a0 = *(const short8*)&Ks[r * 64 + slo];
      short8 a1 = *(const short8*)&Ks[r * 64 + shi];
      f32x4 z = (f32x4){0.f, 0.f, 0.f, 0.f};
      z = __builtin_amdgcn_mfma_f32_16x16x32_bf16(a0, q0f, z, 0, 0, 0);
      z = __builtin_amdgcn_mfma_f32_16x16x32_bf16(a1, q1f, z, 0, 0, 0);
      St[kt] = z;
    }
    __builtin_amdgcn_s_setprio(0);
    if (maskit) {  // uniform branch: only the diagonal tile needs the mask
#pragma unroll
      for (int kt = 0; kt < 4; kt++)
#pragma unroll
        for (int r = 0; r < 4; r++) {
          int s_abs = s0 + kt * 16 + quad * 4 + r;
          St[kt][r] = (s_abs <= t_row) ? St[kt][r] : -3.0e38f;
        }
    }
    float vm = St[0][0];
#pragma unroll
    for (int kt = 0; kt < 4; kt++)
#pragma unroll
      for (int r = 0; r < 4; r++) vm = fmaxf(vm, St[kt][r]);
    vm = fmaxf(vm, __shfl_xor(vm, 16));
    vm = fmaxf(vm, __shfl_xor(vm, 32));
    float mn = fmaxf(m_, vm);
    // T13 defer-rescale: keep old max while growth < 8 (p <= 2^8, safe in f32)
    if (!__all(mn - m_ <= 8.0f)) {
      float alpha = exp2f(m_ - mn);
      m_ = mn;
      l_ *= alpha;
#pragma unroll
      for (int dt = 0; dt < 4; dt++)
#pragma unroll
        for (int r = 0; r < 4; r++) O[dt][r] *= alpha;
    }
    float ps = 0.f;
#pragma unroll
    for (int kt = 0; kt < 4; kt++)
#pragma unroll
      for (int r = 0; r < 4; r++) {
        float p = exp2f(St[kt][r] - m_);
        St[kt][r] = p;
        ps += p;
      }
    ps += __shfl_xor(ps, 16);
    ps += __shfl_xor(ps, 32);
    l_ += ps;

    asm volatile("" ::: "memory");  // order Pw writes after prior Pw reads
#pragma unroll
    for (int kt = 0; kt < 4; kt++) {
      u16x4 pk = {f2bf(St[kt][0]), f2bf(St[kt][1]), f2bf(St[kt][2]), f2bf(St[kt][3])};
      *(u16x4*)&Pw[wave][ln16][kt * 16 + quad * 4] = pk;
    }
    asm volatile("" ::: "memory");  // forbid hoisting Pw reads above writes
    union { u16x8 u; short8 s; } p0, p1;
    p0.u = *(const u16x8*)&Pw[wave][ln16][quad * 8];
    p1.u = *(const u16x8*)&Pw[wave][ln16][32 + quad * 8];
    __builtin_amdgcn_s_setprio(1);
#pragma unroll
    for (int dt = 0; dt < 4; dt++) {
      int r = dt * 16 + ln16;
      short8 v0 = *(const short8*)&VTs[r * 64 + slo];
      short8 v1 = *(const short8*)&VTs[r * 64 + shi];
      O[dt] = __builtin_amdgcn_mfma_f32_16x16x32_bf16(v0, p0.s, O[dt], 0, 0, 0);
      O[dt] = __builtin_amdgcn_mfma_f32_16x16x32_bf16(v1, p1.s, O[dt], 0, 0, 0);
    }
    __builtin_amdgcn_s_setprio(0);
  };

  for (int s0 = 0; s0 <= hi * 64; s0 += 64) {
    // stage K tile [64][64] + V^T tile [64][64] via async global->LDS,
    // 8 rows per issue, 2 issues per wave per array
#pragma unroll
    for (int h = 0; h < 64; h += 32) {
      int base = h + wave * 8;
      gl2lds16(&kp[(size_t)(s0 + base + ri) * 64 + g8 * 8], &Ks[base * 64]);
      gl2lds16(&vp[(size_t)(base + ri) * 512 + s0 + g8 * 8], &VTs[base * 64]);
    }
    __syncthreads();
    if (s0 <= lo * 64) process(bqlo0, bqlo1, t_lo, m_lo, l_lo, Olo, s0, s0 == lo * 64);
    process(bqhi0, bqhi1, t_hi, m_hi, l_hi, Ohi, s0, s0 == hi * 64);
    __syncthreads();
  }

  int b = bh / 6, h = bh % 6;
  float ilo = 1.0f / l_lo, ihi = 1.0f / l_hi;
  size_t base_lo = ((size_t)(b * 512) + t_lo) * 384 + h * 64;
  size_t base_hi = ((size_t)(b * 512) + t_hi) * 384 + h * 64;
#pragma unroll
  for (int dt = 0; dt < 4; dt++) {
    u16x4 plo = {f2bf(Olo[dt][0] * ilo), f2bf(Olo[dt][1] * ilo),
                 f2bf(Olo[dt][2] * ilo), f2bf(Olo[dt][3] * ilo)};
    *(u16x4*)&outg[base_lo + dt * 16 + quad * 4] = plo;
    u16x4 phi = {f2bf(Ohi[dt][0] * ihi), f2bf(Ohi[dt][1] * ihi),
                 f2bf(Ohi[dt][2] * ihi), f2bf(Ohi[dt][3] * ihi)};
    *(u16x4*)&outg[base_hi + dt * 16 + quad * 4] = phi;
  }
}

// ---------------- host ----------------
extern "C" void kernel_launch(void* const* d_in, const int* in_sizes, int n_in,
                              void* d_out, int out_size, void* d_ws, size_t ws_size,
                              hipStream_t stream) {
  const float* x = (const float*)d_in[0];
  const float* Wq = (const float*)d_in[1];
  const float* Wk = (const float*)d_in[2];
  const float* Wv = (const float*)d_in[3];
  const float* Wp = (const float*)d_in[4];
  const float* bp = (const float*)d_in[5];
  const float* g1 = (const float*)d_in[6];
  const float* b1 = (const float*)d_in[7];
  const float* g2 = (const float*)d_in[8];
  const float* b2 = (const float*)d_in[9];
  const float* W1 = (const float*)d_in[10];
  const float* bf1 = (const float*)d_in[11];
  const float* W2 = (const float*)d_in[12];
  const float* bf2 = (const float*)d_in[13];
  float* outp = (float*)d_out;  // fp32 output; also hosts xr between proj and ff2

  char* ws = (char*)d_ws;
  size_t off = 0;
  auto alloc = [&](size_t elems) {
    ushort* p = (ushort*)(ws + off);
    off += elems * 2;
    return p;
  };
  ushort* WqT = alloc((size_t)384 * 384);
  ushort* WkT = alloc((size_t)384 * 384);
  ushort* WvT = alloc((size_t)384 * 384);
  ushort* WpT = alloc((size_t)384 * 384);
  ushort* W1T = alloc((size_t)384 * 1536);
  ushort* W2T = alloc((size_t)1536 * 384);
  ushort* bufq = alloc((size_t)16384 * 384);  // q, later h2
  ushort* m1 = alloc((size_t)16384 * 1536);   // [h1/attn | k | vT | spare], then ff1
  ushort* h1_attn = m1;
  ushort* bufk = m1 + (size_t)16384 * 384;
  ushort* vT = m1 + (size_t)2 * 16384 * 384;

  dim3 tb(32, 8);
  // all 6 weight transposes in one launch
  transpose6_k<<<dim3(48, 12, 6), tb, 0, stream>>>(Wq, Wk, Wv, Wp, W1, W2,
                                                   WqT, WkT, WvT, WpT, W1T, W2T);

  // h1 = ln(x, g1, b1)  [fp32 -> bf16]
  ln_k<<<4096, 256, 0, stream>>>(x, g1, b1, h1_attn);
  // q,k,vT (bf16); q pre-scaled by 0.125*log2(e)
  gemm_k<0, 128><<<dim3(128, 3, 3), 256, 0, stream>>>(
      h1_attn, 384, WqT, WkT, WvT, nullptr, nullptr, bufq, bufk, vT, nullptr);
  // attention -> attn (bf16, overwrites h1 slot)
  attn_k<<<768, 256, 0, stream>>>(bufq, bufk, vT, h1_attn);
  // xr = attn@Wp + bp + x  (fp32, into d_out)
  gemm_k<1, 64><<<dim3(128, 6), 256, 0, stream>>>(
      h1_attn, 384, WpT, nullptr, nullptr, bp, x, nullptr, nullptr, nullptr, outp);
  // h2 = ln(xr, g2, b2)  [fp32 -> bf16, into q slot]
  ln_k<<<4096, 256, 0, stream>>>(outp, g2, b2, bufq);
  // m1 = relu(h2@W1 + bf1)  (bf16)
  gemm_k<2, 128><<<dim3(128, 12), 256, 0, stream>>>(
      bufq, 384, W1T, nullptr, nullptr, bf1, nullptr, m1, nullptr, nullptr, nullptr);
  // out = m1@W2 + bf2 + xr  (fp32, in-place on d_out)
  gemm_k<1, 64><<<dim3(128, 6), 256, 0, stream>>>(
      m1, 1536, W2T, nullptr, nullptr, bf2, outp, nullptr, nullptr, nullptr, outp);
}

// Round 8
// 247.262 us; speedup vs baseline: 1.0916x; 1.0234x over previous
//
#include <hip/hip_runtime.h>
#include <cstdint>
#include <cstddef>

#define DEVINL __device__ __forceinline__

typedef short short8 __attribute__((ext_vector_type(8)));
typedef float f32x4 __attribute__((ext_vector_type(4)));
typedef unsigned short ushort;
typedef ushort u16x8 __attribute__((ext_vector_type(8)));
typedef ushort u16x4 __attribute__((ext_vector_type(4)));

DEVINL float bf2f(ushort u) {
  union { unsigned int i; float f; } v; v.i = ((unsigned int)u) << 16; return v.f;
}
DEVINL ushort f2bf(float f) {
  union { float f; unsigned int i; } v; v.f = f;
  unsigned int u = v.i;
  unsigned int r = u + 0x7fffu + ((u >> 16) & 1u);
  return (ushort)(r >> 16);
}

// Async global->LDS, 16B per lane. LDS dest = wave-uniform base + lane*16.
DEVINL void gl2lds16(const ushort* g, ushort* l) {
  __builtin_amdgcn_global_load_lds(
      (const __attribute__((address_space(1))) void*)g,
      (__attribute__((address_space(3))) void*)l, 16, 0, 0);
}

// ------- fused 6x weight transpose + cast: f32 [R,C] -> bf16 [C,R] ----
// z 0..3: 384x384 (Wq,Wk,Wv,Wp)  z==4: W1 384x1536  z==5: W2 1536x384
__global__ void transpose6_k(const float* __restrict__ Wq, const float* __restrict__ Wk,
                             const float* __restrict__ Wv, const float* __restrict__ Wp,
                             const float* __restrict__ W1, const float* __restrict__ W2,
                             ushort* __restrict__ WqT, ushort* __restrict__ WkT,
                             ushort* __restrict__ WvT, ushort* __restrict__ WpT,
                             ushort* __restrict__ W1T, ushort* __restrict__ W2T) {
  __shared__ float tile[32][33];
  int z = blockIdx.z;
  const float* in;
  ushort* out;
  int R, C, bx, by;
  if (z < 4) {
    if (blockIdx.x >= 12) return;  // uniform early-out, before any barrier
    in = (z == 0) ? Wq : (z == 1) ? Wk : (z == 2) ? Wv : Wp;
    out = (z == 0) ? WqT : (z == 1) ? WkT : (z == 2) ? WvT : WpT;
    R = 384; C = 384; bx = blockIdx.x; by = blockIdx.y;
  } else if (z == 4) {
    in = W1; out = W1T; R = 384; C = 1536; bx = blockIdx.x; by = blockIdx.y;
  } else {
    in = W2; out = W2T; R = 1536; C = 384; bx = blockIdx.y; by = blockIdx.x;
  }
  int tx = threadIdx.x, ty = threadIdx.y;  // (32,8)
  int x = bx * 32 + tx;
#pragma unroll
  for (int i = 0; i < 4; i++) {
    int y = by * 32 + ty + i * 8;
    tile[ty + i * 8][tx] = in[(size_t)y * C + x];
  }
  __syncthreads();
  int x2 = by * 32 + tx;
#pragma unroll
  for (int i = 0; i < 4; i++) {
    int y2 = bx * 32 + ty + i * 8;
    out[(size_t)y2 * R + x2] = f2bf(tile[tx][ty + i * 8]);
  }
}

// ------- LayerNorm: wave per row of 384; fp32 in -> bf16 out ----
__global__ __launch_bounds__(256) void ln_k(const float* __restrict__ x,
                                            const float* __restrict__ g,
                                            const float* __restrict__ b,
                                            ushort* __restrict__ out) {
  int wave = threadIdx.x >> 6;
  int lane = threadIdx.x & 63;
  int row = blockIdx.x * 4 + wave;
  const float* xr = x + (size_t)row * 384;
  float v[6];
#pragma unroll
  for (int j = 0; j < 3; j++) {
    float2 p = *(const float2*)(xr + lane * 2 + j * 128);
    v[2 * j] = p.x;
    v[2 * j + 1] = p.y;
  }
  float s = v[0] + v[1] + v[2] + v[3] + v[4] + v[5];
#pragma unroll
  for (int off = 32; off; off >>= 1) s += __shfl_xor(s, off);
  float mu = s * (1.0f / 384.0f);
  float s2 = 0.f;
#pragma unroll
  for (int j = 0; j < 6; j++) { float d = v[j] - mu; s2 += d * d; }
#pragma unroll
  for (int off = 32; off; off >>= 1) s2 += __shfl_xor(s2, off);
  float rs = rsqrtf(s2 * (1.0f / 384.0f) + 1e-5f);
  ushort* orow = out + (size_t)row * 384;
#pragma unroll
  for (int j = 0; j < 3; j++) {
    int c = lane * 2 + j * 128;
    float2 pg = *(const float2*)(g + c);
    float2 pb = *(const float2*)(b + c);
    float y0 = (v[2 * j] - mu) * rs * pg.x + pb.x;
    float y1 = (v[2 * j + 1] - mu) * rs * pg.y + pb.y;
    uint32_t po = (uint32_t)f2bf(y0) | ((uint32_t)f2bf(y1) << 16);
    *(uint32_t*)(orow + c) = po;
  }
}

// ------- GEMM: C[M,N] = A[M,K](bf16) @ W[K,N], W as bf16 WT[N,K] ----
// BK=64, XOR-8 chunk swizzle staging: LDS slot s of row r holds global
// chunk s^(r&7); fragment reads use slot (ks*4+q4)^(r&7) -> conflict-free
// b128 reads. Staging BW is CONCURRENCY-limited (R2-R7: ~12 TB/s at
// 3 blocks/CU; 5.7-8 TB/s at <=1.5; KU=2 batching also negative) ->
// keep the simple 2-barrier loop, >=768 blocks, 32KB LDS. Final form.
// MODE 0 (TN=128): QKV — grid.z selects Wq/Wk/Wv; q (pre-scaled by
//                  0.125*log2e), k -> [B,H,T,D]; v -> [B,H,D,T]
// MODE 1 (TN=64):  outf = A@W + bias + residf (fp32, ld 384) [proj, ff2]
// MODE 2 (TN=128): outa = bf16(relu(A@W + bias)) (ld 1536)   [ff1]
template <int MODE, int TN>
__global__ __launch_bounds__(256) void gemm_k(
    const ushort* __restrict__ A, int K,
    const ushort* __restrict__ WTa, const ushort* __restrict__ WTb,
    const ushort* __restrict__ WTc,
    const float* __restrict__ bias, const float* residf,
    ushort* __restrict__ outa, ushort* __restrict__ outb,
    ushort* __restrict__ outc, float* outf) {
  constexpr int NJ = TN / 32;
  __shared__ __align__(16) ushort As[128 * 64];
  __shared__ __align__(16) ushort Bs[TN * 64];
  int tid = threadIdx.x;
  int lane = tid & 63, wave = tid >> 6;
  int wm = wave & 1, wn = wave >> 1;
  int q4 = lane >> 4, ln16 = lane & 15;
  int rowBase = blockIdx.x * 128;
  int colBase = blockIdx.y * TN;

  const ushort* WT;
  if (MODE == 0) {
    int z = blockIdx.z;
    WT = (z == 0) ? WTa : (z == 1) ? WTb : WTc;
  } else {
    WT = WTa;
  }

  f32x4 acc[4][NJ];
#pragma unroll
  for (int i = 0; i < 4; i++)
#pragma unroll
    for (int j = 0; j < NJ; j++) acc[i][j] = (f32x4){0.f, 0.f, 0.f, 0.f};

  int ri = lane >> 3;             // row within 8-row issue group
  int g8 = (lane & 7) ^ ri;       // swizzled global 8-elem chunk

  for (int kb = 0; kb < K; kb += 64) {
#pragma unroll
    for (int h = 0; h < 128; h += 32) {
      int base = h + wave * 8;
      gl2lds16(&A[(size_t)(rowBase + base + ri) * K + kb + g8 * 8], &As[base * 64]);
    }
#pragma unroll
    for (int h = 0; h < TN; h += 32) {
      int base = h + wave * 8;
      gl2lds16(&WT[(size_t)(colBase + base + ri) * K + kb + g8 * 8], &Bs[base * 64]);
    }
    __syncthreads();
#pragma unroll
    for (int ks = 0; ks < 2; ks++) {
      short8 af[4], bfr[NJ];
#pragma unroll
      for (int i = 0; i < 4; i++) {
        int ar = wm * 64 + i * 16 + ln16;
        int slot = (ks * 4 + q4) ^ (ar & 7);
        af[i] = *(const short8*)&As[ar * 64 + slot * 8];
      }
#pragma unroll
      for (int j = 0; j < NJ; j++) {
        int br = wn * (TN / 2) + j * 16 + ln16;
        int slot = (ks * 4 + q4) ^ (br & 7);
        bfr[j] = *(const short8*)&Bs[br * 64 + slot * 8];
      }
#pragma unroll
      for (int i = 0; i < 4; i++)
#pragma unroll
        for (int j = 0; j < NJ; j++)
          acc[i][j] = __builtin_amdgcn_mfma_f32_16x16x32_bf16(af[i], bfr[j], acc[i][j], 0, 0, 0);
    }
    __syncthreads();
  }

#pragma unroll
  for (int i = 0; i < 4; i++) {
#pragma unroll
    for (int j = 0; j < NJ; j++) {
      int row0 = rowBase + wm * 64 + i * 16 + q4 * 4;
      int col = colBase + wn * (TN / 2) + j * 16 + ln16;
      if (MODE == 0) {
        int z = blockIdx.z;
        if (z < 2) {
          // q is pre-scaled by qk-scale * log2(e) so attention skips the mul
          float sc = (z == 0) ? 0.18033688011112f : 1.0f;
          ushort* o = (z == 0) ? outa : outb;
#pragma unroll
          for (int r = 0; r < 4; r++) {
            int row = row0 + r;
            int bb = row >> 9, t = row & 511, h = col >> 6, d = col & 63;
            o[(((size_t)(bb * 6 + h) * 512) + t) * 64 + d] = f2bf(acc[i][j][r] * sc);
          }
        } else {
          int bb = row0 >> 9, t0 = row0 & 511, h = col >> 6, d = col & 63;
          u16x4 pk = {f2bf(acc[i][j][0]), f2bf(acc[i][j][1]), f2bf(acc[i][j][2]),
                      f2bf(acc[i][j][3])};
          *(u16x4*)&outc[(((size_t)(bb * 6 + h) * 64) + d) * 512 + t0] = pk;
        }
      } else if (MODE == 1) {
        float bcol = bias[col];
#pragma unroll
        for (int r = 0; r < 4; r++) {
          size_t idx = (size_t)(row0 + r) * 384 + col;
          outf[idx] = acc[i][j][r] + bcol + residf[idx];
        }
      } else {
        float bcol = bias[col];
#pragma unroll
        for (int r = 0; r < 4; r++) {
          size_t idx = (size_t)(row0 + r) * 1536 + col;
          float vv = acc[i][j][r] + bcol;
          outa[idx] = f2bf(vv > 0.f ? vv : 0.f);
        }
      }
    }
  }
}

// ------- flash attention, paired q-tiles + XCD-local bh ----
// Block handles q-tiles pr and 7-pr of one (b,h): uniform work (9 units),
// shared K/V staging. S^T = K·Q^T; softmax in-register; O^T = V^T·P^T.
// K/V DOUBLE-BUFFERED (T3/T14 regime: long compute phase per tile hides
// the next tile's arrival — unlike the GEMMs, where cross-block TLP
// already covered it). Per tile: STAGE(next) issued BEFORE the counted
// vmcnt(4) wait for the current tile (4 issues/wave/tile, FIFO retire
// makes the count exact); raw s_barrier pair per tile (same barrier
// count as before — only the wait point moves). LDS 43KB -> 3 blocks/CU.
// K/V staged via global_load_lds with XOR-8 chunk swizzle (linear [64][64]
// LDS, slot s of row r = global chunk s^(r&7)) -> conflict-free b128 reads.
// Q pre-scaled at QKV epilogue; causal mask applied only on diagonal tile;
// T13 defer-rescale skips O-rescale while running max grows < 8 (log2 dom).
__global__ __launch_bounds__(256) void attn_k(const ushort* __restrict__ qg,
                                              const ushort* __restrict__ kg,
                                              const ushort* __restrict__ vtg,
                                              ushort* __restrict__ outg) {
  __shared__ __align__(16) ushort Ks[2][64 * 64];
  __shared__ __align__(16) ushort VTs[2][64 * 64];
  __shared__ __align__(16) ushort Pw[4][16][88];
  int tid = threadIdx.x, lane = tid & 63, wave = tid >> 6;
  int l = blockIdx.x;
  int xcd = l & 7, m = l >> 3;
  int bh = xcd * 24 + (m >> 2);
  int pr = m & 3;           // pair index: q-tiles pr (lo) and 7-pr (hi)
  int lo = pr, hi = 7 - pr;
  int quad = lane >> 4, ln16 = lane & 15;
  int x7 = ln16 & 7;
  int slo = (quad ^ x7) * 8;   // swizzled elem offset, cols 0..31
  int shi = slo ^ 32;          // cols 32..63 ((quad+4)^x7 == (quad^x7)^4)

  const ushort* qp = qg + (size_t)bh * 512 * 64;
  const ushort* kp = kg + (size_t)bh * 512 * 64;
  const ushort* vp = vtg + (size_t)bh * 64 * 512;

  int ri = lane >> 3;          // row within 8-row issue group
  int g8 = (lane & 7) ^ ri;    // swizzled global 8-elem chunk

  int t_lo = lo * 64 + wave * 16 + ln16;
  int t_hi = hi * 64 + wave * 16 + ln16;
  short8 bqlo0 = *(const short8*)&qp[(size_t)t_lo * 64 + quad * 8];
  short8 bqlo1 = *(const short8*)&qp[(size_t)t_lo * 64 + 32 + quad * 8];
  short8 bqhi0 = *(const short8*)&qp[(size_t)t_hi * 64 + quad * 8];
  short8 bqhi1 = *(const short8*)&qp[(size_t)t_hi * 64 + 32 + quad * 8];

  f32x4 Olo[4], Ohi[4];
#pragma unroll
  for (int dt = 0; dt < 4; dt++) {
    Olo[dt] = (f32x4){0.f, 0.f, 0.f, 0.f};
    Ohi[dt] = (f32x4){0.f, 0.f, 0.f, 0.f};
  }
  float m_lo = -3.0e38f, l_lo = 0.f, m_hi = -3.0e38f, l_hi = 0.f;

  // exactly 4 global_load_lds issues per wave per tile: K(h0),V(h0),K(h32),V(h32)
  auto STAGEKV = [&](int buf, int s0) {
#pragma unroll
    for (int h = 0; h < 64; h += 32) {
      int base = h + wave * 8;
      gl2lds16(&kp[(size_t)(s0 + base + ri) * 64 + g8 * 8], &Ks[buf][base * 64]);
      gl2lds16(&vp[(size_t)(base + ri) * 512 + s0 + g8 * 8], &VTs[buf][base * 64]);
    }
  };

  auto process = [&](short8 q0f, short8 q1f, int t_row, float& m_, float& l_,
                     f32x4* O, int s0, bool maskit,
                     const ushort* Kb, const ushort* Vb) {
    f32x4 St[4];
    __builtin_amdgcn_s_setprio(1);
#pragma unroll
    for (int kt = 0; kt < 4; kt++) {
      int r = kt * 16 + ln16;
      short8 a0 = *(const short8*)&Kb[r * 64 + slo];
      short8 a1 = *(const short8*)&Kb[r * 64 + shi];
      f32x4 z = (f32x4){0.f, 0.f, 0.f, 0.f};
      z = __builtin_amdgcn_mfma_f32_16x16x32_bf16(a0, q0f, z, 0, 0, 0);
      z = __builtin_amdgcn_mfma_f32_16x16x32_bf16(a1, q1f, z, 0, 0, 0);
      St[kt] = z;
    }
    __builtin_amdgcn_s_setprio(0);
    if (maskit) {  // uniform branch: only the diagonal tile needs the mask
#pragma unroll
      for (int kt = 0; kt < 4; kt++)
#pragma unroll
        for (int r = 0; r < 4; r++) {
          int s_abs = s0 + kt * 16 + quad * 4 + r;
          St[kt][r] = (s_abs <= t_row) ? St[kt][r] : -3.0e38f;
        }
    }
    float vm = St[0][0];
#pragma unroll
    for (int kt = 0; kt < 4; kt++)
#pragma unroll
      for (int r = 0; r < 4; r++) vm = fmaxf(vm, St[kt][r]);
    vm = fmaxf(vm, __shfl_xor(vm, 16));
    vm = fmaxf(vm, __shfl_xor(vm, 32));
    float mn = fmaxf(m_, vm);
    // T13 defer-rescale: keep old max while growth < 8 (p <= 2^8, safe in f32)
    if (!__all(mn - m_ <= 8.0f)) {
      float alpha = exp2f(m_ - mn);
      m_ = mn;
      l_ *= alpha;
#pragma unroll
      for (int dt = 0; dt < 4; dt++)
#pragma unroll
        for (int r = 0; r < 4; r++) O[dt][r] *= alpha;
    }
    float ps = 0.f;
#pragma unroll
    for (int kt = 0; kt < 4; kt++)
#pragma unroll
      for (int r = 0; r < 4; r++) {
        float p = exp2f(St[kt][r] - m_);
        St[kt][r] = p;
        ps += p;
      }
    ps += __shfl_xor(ps, 16);
    ps += __shfl_xor(ps, 32);
    l_ += ps;

    asm volatile("" ::: "memory");  // order Pw writes after prior Pw reads
#pragma unroll
    for (int kt = 0; kt < 4; kt++) {
      u16x4 pk = {f2bf(St[kt][0]), f2bf(St[kt][1]), f2bf(St[kt][2]), f2bf(St[kt][3])};
      *(u16x4*)&Pw[wave][ln16][kt * 16 + quad * 4] = pk;
    }
    asm volatile("" ::: "memory");  // forbid hoisting Pw reads above writes
    union { u16x8 u; short8 s; } p0, p1;
    p0.u = *(const u16x8*)&Pw[wave][ln16][quad * 8];
    p1.u = *(const u16x8*)&Pw[wave][ln16][32 + quad * 8];
    __builtin_amdgcn_s_setprio(1);
#pragma unroll
    for (int dt = 0; dt < 4; dt++) {
      int r = dt * 16 + ln16;
      short8 v0 = *(const short8*)&Vb[r * 64 + slo];
      short8 v1 = *(const short8*)&Vb[r * 64 + shi];
      O[dt] = __builtin_amdgcn_mfma_f32_16x16x32_bf16(v0, p0.s, O[dt], 0, 0, 0);
      O[dt] = __builtin_amdgcn_mfma_f32_16x16x32_bf16(v1, p1.s, O[dt], 0, 0, 0);
    }
    __builtin_amdgcn_s_setprio(0);
  };

  int nt = hi + 1;  // tiles 0..hi
  STAGEKV(0, 0);
  for (int t = 0; t < nt; ++t) {
    int cur = t & 1;
    // issue next tile FIRST, then wait only for the current tile's 4 loads
    if (t + 1 < nt) {
      STAGEKV(cur ^ 1, (t + 1) << 6);
      asm volatile("s_waitcnt vmcnt(4)" ::: "memory");
    } else {
      asm volatile("s_waitcnt vmcnt(0)" ::: "memory");
    }
    __builtin_amdgcn_sched_barrier(0);
    __builtin_amdgcn_s_barrier();   // all waves' cur-tile staging complete
    __builtin_amdgcn_sched_barrier(0);
    int s0 = t << 6;
    if (s0 <= lo * 64)
      process(bqlo0, bqlo1, t_lo, m_lo, l_lo, Olo, s0, s0 == lo * 64,
              &Ks[cur][0], &VTs[cur][0]);
    process(bqhi0, bqhi1, t_hi, m_hi, l_hi, Ohi, s0, s0 == hi * 64,
            &Ks[cur][0], &VTs[cur][0]);
    __builtin_amdgcn_sched_barrier(0);
    __builtin_amdgcn_s_barrier();   // all reads of buf[cur] done before t+2 restages it
  }

  int b = bh / 6, h = bh % 6;
  float ilo = 1.0f / l_lo, ihi = 1.0f / l_hi;
  size_t base_lo = ((size_t)(b * 512) + t_lo) * 384 + h * 64;
  size_t base_hi = ((size_t)(b * 512) + t_hi) * 384 + h * 64;
#pragma unroll
  for (int dt = 0; dt < 4; dt++) {
    u16x4 plo = {f2bf(Olo[dt][0] * ilo), f2bf(Olo[dt][1] * ilo),
                 f2bf(Olo[dt][2] * ilo), f2bf(Olo[dt][3] * ilo)};
    *(u16x4*)&outg[base_lo + dt * 16 + quad * 4] = plo;
    u16x4 phi = {f2bf(Ohi[dt][0] * ihi), f2bf(Ohi[dt][1] * ihi),
                 f2bf(Ohi[dt][2] * ihi), f2bf(Ohi[dt][3] * ihi)};
    *(u16x4*)&outg[base_hi + dt * 16 + quad * 4] = phi;
  }
}

// ---------------- host ----------------
extern "C" void kernel_launch(void* const* d_in, const int* in_sizes, int n_in,
                              void* d_out, int out_size, void* d_ws, size_t ws_size,
                              hipStream_t stream) {
  const float* x = (const float*)d_in[0];
  const float* Wq = (const float*)d_in[1];
  const float* Wk = (const float*)d_in[2];
  const float* Wv = (const float*)d_in[3];
  const float* Wp = (const float*)d_in[4];
  const float* bp = (const float*)d_in[5];
  const float* g1 = (const float*)d_in[6];
  const float* b1 = (const float*)d_in[7];
  const float* g2 = (const float*)d_in[8];
  const float* b2 = (const float*)d_in[9];
  const float* W1 = (const float*)d_in[10];
  const float* bf1 = (const float*)d_in[11];
  const float* W2 = (const float*)d_in[12];
  const float* bf2 = (const float*)d_in[13];
  float* outp = (float*)d_out;  // fp32 output; also hosts xr between proj and ff2

  char* ws = (char*)d_ws;
  size_t off = 0;
  auto alloc = [&](size_t elems) {
    ushort* p = (ushort*)(ws + off);
    off += elems * 2;
    return p;
  };
  ushort* WqT = alloc((size_t)384 * 384);
  ushort* WkT = alloc((size_t)384 * 384);
  ushort* WvT = alloc((size_t)384 * 384);
  ushort* WpT = alloc((size_t)384 * 384);
  ushort* W1T = alloc((size_t)384 * 1536);
  ushort* W2T = alloc((size_t)1536 * 384);
  ushort* bufq = alloc((size_t)16384 * 384);  // q, later h2
  ushort* m1 = alloc((size_t)16384 * 1536);   // [h1/attn | k | vT | spare], then ff1
  ushort* h1_attn = m1;
  ushort* bufk = m1 + (size_t)16384 * 384;
  ushort* vT = m1 + (size_t)2 * 16384 * 384;

  dim3 tb(32, 8);
  // all 6 weight transposes in one launch
  transpose6_k<<<dim3(48, 12, 6), tb, 0, stream>>>(Wq, Wk, Wv, Wp, W1, W2,
                                                   WqT, WkT, WvT, WpT, W1T, W2T);

  // h1 = ln(x, g1, b1)  [fp32 -> bf16]
  ln_k<<<4096, 256, 0, stream>>>(x, g1, b1, h1_attn);
  // q,k,vT (bf16); q pre-scaled by 0.125*log2(e)
  gemm_k<0, 128><<<dim3(128, 3, 3), 256, 0, stream>>>(
      h1_attn, 384, WqT, WkT, WvT, nullptr, nullptr, bufq, bufk, vT, nullptr);
  // attention -> attn (bf16, overwrites h1 slot)
  attn_k<<<768, 256, 0, stream>>>(bufq, bufk, vT, h1_attn);
  // xr = attn@Wp + bp + x  (fp32, into d_out)
  gemm_k<1, 64><<<dim3(128, 6), 256, 0, stream>>>(
      h1_attn, 384, WpT, nullptr, nullptr, bp, x, nullptr, nullptr, nullptr, outp);
  // h2 = ln(xr, g2, b2)  [fp32 -> bf16, into q slot]
  ln_k<<<4096, 256, 0, stream>>>(outp, g2, b2, bufq);
  // m1 = relu(h2@W1 + bf1)  (bf16)
  gemm_k<2, 128><<<dim3(128, 12), 256, 0, stream>>>(
      bufq, 384, W1T, nullptr, nullptr, bf1, nullptr, m1, nullptr, nullptr, nullptr);
  // out = m1@W2 + bf2 + xr  (fp32, in-place on d_out)
  gemm_k<1, 64><<<dim3(128, 6), 256, 0, stream>>>(
      m1, 1536, W2T, nullptr, nullptr, bf2, outp, nullptr, nullptr, nullptr, outp);
}